// Round 7
// baseline (333.548 us; speedup 1.0000x reference)
//
#include <hip/hip_runtime.h>
#include <hip/hip_bf16.h>
#include <math.h>

#define HIDDEN 2048
#define EINTER 1024
#define NEXP 8
#define VOCAB 100000
#define TPE (VOCAB / NEXP)   // 12500

typedef unsigned short u16;
typedef __attribute__((ext_vector_type(8))) short short8;   // 8 bf16 (4 VGPRs)
typedef __attribute__((ext_vector_type(4))) float f32x4;

__device__ __forceinline__ u16 f2bf(float f) {
  union { float f; unsigned u; } v; v.f = f;
  unsigned r = v.u + 0x7fffu + ((v.u >> 16) & 1u);   // RNE, finite inputs only
  return (u16)(r >> 16);
}

__device__ __forceinline__ float f4get(const float4& a, int i) {
  return i == 0 ? a.x : i == 1 ? a.y : i == 2 ? a.z : a.w;
}

__device__ __forceinline__ void gl2lds16(const u16* g, u16* l) {
  __builtin_amdgcn_global_load_lds(
      (const __attribute__((address_space(1))) unsigned int*)g,
      (__attribute__((address_space(3))) unsigned int*)l, 16, 0, 0);
}

// ---------------- routing (device body, fused into prep grid) ----------------
// hdr ints: [0..7]=cnt[e], [8..15]=off[e], [16]=n_tiles, [32..95]=worklist
__device__ void route_body(const int* __restrict__ ids, int T,
                           int* __restrict__ hdr, int* __restrict__ src_of) {
  __shared__ int cnt[NEXP], cur[NEXP];
  int tid = threadIdx.x;
  if (tid < NEXP) cnt[tid] = 0;
  __syncthreads();
  for (int t = tid; t < T; t += blockDim.x) {
    int id = ids[t]; id = min(max(id, 0), VOCAB - 1);
    int e = min(id / TPE, NEXP - 1);
    atomicAdd(&cnt[e], 1);
  }
  __syncthreads();
  if (tid == 0) {
    int acc = 0, nt = 0;
    for (int e = 0; e < NEXP; e++) {
      cur[e] = acc;
      hdr[e] = cnt[e];
      hdr[8 + e] = acc;
      int tiles = (cnt[e] + 127) >> 7;
      for (int m = 0; m < tiles; m++) hdr[32 + nt++] = (m << 3) | e;
      acc += cnt[e];
    }
    hdr[16] = nt;
  }
  __syncthreads();
  for (int t = tid; t < T; t += blockDim.x) {
    int id = ids[t]; id = min(max(id, 0), VOCAB - 1);
    int e = min(id / TPE, NEXP - 1);
    int pos = atomicAdd(&cur[e], 1);
    src_of[pos] = t;
  }
}

// ---------------- weight prep: fp32 [K][N] -> bf16 tiles [e][n_blk128][k_blk64] ----------------
// Persistent 2-deep register pipeline: each block does 4 consecutive tiles,
// issuing tile i+1's 8 fp32x4 loads (regset (i+1)&1) before converting tile i,
// so HBM latency hides under convert+LDS+store of the current tile (T14 pattern;
// compiler's counted vmcnt(8) keeps them in flight - register loads, not LDS-dest,
// so barriers need not drain them). z==3: routing slice.
__launch_bounds__(256, 4)
__global__ void prep_kernel(const float* __restrict__ gate, const float* __restrict__ up,
                            const float* __restrict__ down,
                            u16* __restrict__ gatet, u16* __restrict__ upt,
                            u16* __restrict__ downt,
                            const int* __restrict__ ids, int T,
                            int* __restrict__ hdr, int* __restrict__ src_of) {
  int z = blockIdx.z, e = blockIdx.y;
  if (z == 3) {
    if (blockIdx.x == 0 && blockIdx.y == 0) route_body(ids, T, hdr, src_of);
    return;
  }
  const float* W; u16* Wt; int K, N;
  if (z == 0)      { W = gate; Wt = gatet; K = 2048; N = 1024; }
  else if (z == 1) { W = up;   Wt = upt;   K = 2048; N = 1024; }
  else             { W = down; Wt = downt; K = 1024; N = 2048; }
  W += (size_t)e * K * N;
  int nkt = K >> 6, ntx = N >> 7;

  __shared__ u16 Ts[128 * 64];    // [n][k] swizzled, 16 KB
  int t = threadIdx.x;
  int kkb = (t >> 5) << 2;        // 0..28
  int cc  = (t & 31) << 2;        // n col 0..124

  float4 v[2][8];                 // two regsets x 8 fp32x4 = 64 VGPRs data

  int idx0 = blockIdx.x << 2;     // 4 consecutive tiles (k-sequential)

  // issue the 8 loads of tile idx into regset p
  #define ISSUE(p, idx)                                                        \
    {                                                                          \
      int tn_ = (idx) / nkt, tk_ = (idx) - tn_ * nkt;                          \
      const float* Wb_ = W + ((size_t)(tk_ << 6)) * N + (tn_ << 7) + cc;       \
      _Pragma("unroll")                                                        \
      for (int r = 0; r < 2; r++)                                              \
        _Pragma("unroll")                                                      \
        for (int i = 0; i < 4; i++)                                            \
          v[p][(r << 2) + i] =                                                 \
              *(const float4*)(Wb_ + (size_t)(kkb + (r << 5) + i) * N);        \
    }

  ISSUE(0, idx0);
  __builtin_amdgcn_sched_barrier(0);

  #pragma unroll
  for (int it = 0; it < 4; it++) {
    if (it < 3) {
      ISSUE((it + 1) & 1, idx0 + it + 1);
      __builtin_amdgcn_sched_barrier(0);   // pin issue before convert of tile it
    }
    __syncthreads();                        // Ts free (phase2 of tile it-1 done)
    // convert regset it&1 -> Ts (vmcnt(8): next tile's loads stay in flight)
    {
      const int cs = it & 1;
      #pragma unroll
      for (int r = 0; r < 2; r++) {
        int kk = kkb + (r << 5);           // local k 0..63
        int cbase = kk >> 3, klo = kk & 7; // cbase 0..7, klo in {0,4}
        #pragma unroll
        for (int i2 = 0; i2 < 4; i2++) {
          int n_loc = cc + i2;
          int cp = cbase ^ ((n_loc >> 2) & 7);
          unsigned lo = (unsigned)f2bf(f4get(v[cs][(r << 2) + 0], i2)) |
                        ((unsigned)f2bf(f4get(v[cs][(r << 2) + 1], i2)) << 16);
          unsigned hi = (unsigned)f2bf(f4get(v[cs][(r << 2) + 2], i2)) |
                        ((unsigned)f2bf(f4get(v[cs][(r << 2) + 3], i2)) << 16);
          uint2 pk; pk.x = lo; pk.y = hi;
          *(uint2*)&Ts[n_loc * 64 + (cp << 3) + klo] = pk;
        }
      }
    }
    __syncthreads();
    // phase 2: b128 de-swizzle reads, contiguous 1KB/wave global writes (tile it)
    {
      int idx = idx0 + it;
      int tn_ = idx / nkt, tk_ = idx - tn_ * nkt;
      size_t tile0 = ((size_t)e * ntx + tn_) * (size_t)nkt + tk_;
      uint4* ob = (uint4*)Wt + tile0 * 1024;
      #pragma unroll
      for (int it2 = 0; it2 < 4; it2++) {
        int cid = (it2 << 8) + t;       // 0..1023
        int n_loc = cid >> 3, p = cid & 7;
        int cp = p ^ ((n_loc >> 2) & 7);
        uint4 val = *(const uint4*)&Ts[n_loc * 64 + (cp << 3)];
        ob[(n_loc << 3) + p] = val;
      }
    }
  }
  #undef ISSUE
}

// ---------------- gather tokens -> bf16 rows ----------------
__global__ void gather_kernel(const float* __restrict__ x,
                              const int* __restrict__ src_of,
                              u16* __restrict__ Xg) {
  int p = blockIdx.x;
  int t = src_of[p];
  int c = threadIdx.x;
  const float4* src = (const float4*)(x + (size_t)t * HIDDEN) + c * 2;
  float4 a = src[0], b = src[1];
  union { u16 s[8]; uint4 v; } o;
  o.s[0] = f2bf(a.x); o.s[1] = f2bf(a.y); o.s[2] = f2bf(a.z); o.s[3] = f2bf(a.w);
  o.s[4] = f2bf(b.x); o.s[5] = f2bf(b.y); o.s[6] = f2bf(b.z); o.s[7] = f2bf(b.w);
  *((uint4*)(Xg + (size_t)p * HIDDEN) + c) = o.v;
}

// ---------------- gemm1: H = silu(Xg@Wg) * (Xg@Wu), 128m x 64n tiles ----------------
// Single-buffer m97 structure. LDS tiles XOR-swizzled both sides (rule #21):
// linear gl2lds dest + pre-swizzled per-lane global source + XOR'd read column.
__launch_bounds__(256, 4)
__global__ void gemm1_kernel(const u16* __restrict__ Xg, const u16* __restrict__ gatet,
                             const u16* __restrict__ upt, u16* __restrict__ H,
                             const int* __restrict__ hdr, int T) {
  int ntile = hdr[16];
  if ((int)blockIdx.x >= ntile) return;
  int packed = hdr[32 + blockIdx.x];
  int e = packed & 7, mt = packed >> 3;
  int Me = hdr[e], base = hdr[8 + e];
  int row0 = base + (mt << 7);
  int valid = min(128, base + Me - row0);
  int n0 = blockIdx.y << 6;                          // 0..960
  size_t ebase = (size_t)e * (2048 * 1024);
  size_t tbase = ((size_t)(n0 >> 7) * 32) * 8192 + (size_t)((n0 >> 6) & 1) * 4096;
  const u16* gW = gatet + ebase + tbase;
  const u16* uW = upt   + ebase + tbase;

  __shared__ u16 As[128][64];   // 16 KB
  __shared__ u16 Bg[64][64];    // 8 KB
  __shared__ u16 Bu[64][64];    // 8 KB

  int tid = threadIdx.x, lane = tid & 63, wv = tid >> 6;
  int wm = wv >> 1, wn = wv & 1;
  int quad = lane >> 4, ln = lane & 15;
  // staging swizzle: LDS slot (row r = 8c+(lane>>3), chunk p = lane&7) receives
  // logical k-chunk p ^ (r&7); r&7 == lane>>3, so source chunk = (lane&7)^(lane>>3).
  int sw = (((lane & 7) ^ (lane >> 3)) << 3);        // u16 offset within 128B row

  f32x4 accG[4][2] = {};
  f32x4 accU[4][2] = {};

  for (int k0 = 0; k0 < 2048; k0 += 64) {
    size_t woff = (size_t)(k0 >> 6) * 8192 + ((size_t)(lane >> 3) << 6) + sw;
    __syncthreads();
    #pragma unroll
    for (int r = 0; r < 4; r++) {
      int c = (wv << 2) + r;                 // 16 chunks of 8 rows
      int arow = (c << 3) + (lane >> 3);
      int gr = min(row0 + arow, T - 1);      // clamped rows masked in epilogue
      gl2lds16(Xg + (size_t)gr * 2048 + k0 + sw, &As[0][0] + (c << 9));
    }
    #pragma unroll
    for (int r = 0; r < 2; r++) {
      int c = (wv << 1) + r;                 // 8 chunks, contiguous 128B segments
      gl2lds16(gW + woff + (c << 9), &Bg[0][0] + (c << 9));
      gl2lds16(uW + woff + (c << 9), &Bu[0][0] + (c << 9));
    }
    __syncthreads();
    #pragma unroll
    for (int s = 0; s < 2; s++) {
      // logical chunk (s<<2)|quad lives at physical chunk ^(row&7); row&7 == ln&7
      int col = ((((s << 2) | quad) ^ (ln & 7)) << 3);
      short8 a[4], bg[2], bu[2];
      #pragma unroll
      for (int i = 0; i < 4; i++) {
        int m = (wm << 6) + (i << 4) + ln;
        a[i] = *(const short8*)&As[m][col];
      }
      #pragma unroll
      for (int j = 0; j < 2; j++) {
        int n = (wn << 5) + (j << 4) + ln;
        bg[j] = *(const short8*)&Bg[n][col];
        bu[j] = *(const short8*)&Bu[n][col];
      }
      #pragma unroll
      for (int i = 0; i < 4; i++)
        #pragma unroll
        for (int j = 0; j < 2; j++) {
          accG[i][j] = __builtin_amdgcn_mfma_f32_16x16x32_bf16(a[i], bg[j], accG[i][j], 0, 0, 0);
          accU[i][j] = __builtin_amdgcn_mfma_f32_16x16x32_bf16(a[i], bu[j], accU[i][j], 0, 0, 0);
        }
    }
  }
  #pragma unroll
  for (int i = 0; i < 4; i++) {
    #pragma unroll
    for (int r = 0; r < 4; r++) {
      int rl = (wm << 6) + (i << 4) + (quad << 2) + r;
      if (rl < valid) {
        u16* orow = H + (size_t)(row0 + rl) * EINTER + n0 + (wn << 5) + ln;
        #pragma unroll
        for (int j = 0; j < 2; j++) {
          float g = accG[i][j][r], u = accU[i][j][r];
          orow[j << 4] = f2bf(g / (1.f + __expf(-g)) * u);
        }
      }
    }
  }
}

// ---------------- gemm2: out[src_of[p]] = H[p] @ down, 128x128, single-buffer + swizzle ----------------
__launch_bounds__(256, 4)
__global__ void gemm2_kernel(const u16* __restrict__ Hb, const u16* __restrict__ downt,
                             float* __restrict__ out, const int* __restrict__ src_of,
                             const int* __restrict__ hdr, int T) {
  int ntile = hdr[16];
  if ((int)blockIdx.x >= ntile) return;
  int packed = hdr[32 + blockIdx.x];
  int e = packed & 7, mt = packed >> 3;
  int Me = hdr[e], base = hdr[8 + e];
  int row0 = base + (mt << 7);
  int valid = min(128, base + Me - row0);
  int n0 = blockIdx.y << 7;
  const u16* wbase = downt + (size_t)e * (2048 * 1024)
                   + ((size_t)(n0 >> 7) * 16) * 8192;

  __shared__ u16 As[128][64];
  __shared__ u16 Bs[128][64];

  int tid = threadIdx.x, lane = tid & 63, wv = tid >> 6;
  int wm = wv >> 1, wn = wv & 1;
  int quad = lane >> 4, ln = lane & 15;
  int sw = (((lane & 7) ^ (lane >> 3)) << 3);

  f32x4 acc[4][4] = {};

  for (int k0 = 0; k0 < 1024; k0 += 64) {
    size_t woff = (size_t)(k0 >> 6) * 8192 + ((size_t)(lane >> 3) << 6) + sw;
    __syncthreads();
    #pragma unroll
    for (int r = 0; r < 4; r++) {
      int c = (wv << 2) + r;
      int arow = (c << 3) + (lane >> 3);
      int gr = min(row0 + arow, T - 1);
      gl2lds16(Hb + (size_t)gr * 1024 + k0 + sw, &As[0][0] + (c << 9));
      gl2lds16(wbase + woff + (c << 9), &Bs[0][0] + (c << 9));
    }
    __syncthreads();
    #pragma unroll
    for (int s = 0; s < 2; s++) {
      int col = ((((s << 2) | quad) ^ (ln & 7)) << 3);
      short8 a[4], b[4];
      #pragma unroll
      for (int i = 0; i < 4; i++) {
        int m = (wm << 6) + (i << 4) + ln;
        a[i] = *(const short8*)&As[m][col];
        int n = (wn << 6) + (i << 4) + ln;
        b[i] = *(const short8*)&Bs[n][col];
      }
      #pragma unroll
      for (int i = 0; i < 4; i++)
        #pragma unroll
        for (int j = 0; j < 4; j++)
          acc[i][j] = __builtin_amdgcn_mfma_f32_16x16x32_bf16(a[i], b[j], acc[i][j], 0, 0, 0);
    }
  }
  #pragma unroll
  for (int i = 0; i < 4; i++) {
    #pragma unroll
    for (int r = 0; r < 4; r++) {
      int rl = (wm << 6) + (i << 4) + (quad << 2) + r;
      if (rl < valid) {
        int t = src_of[row0 + rl];
        float* orow = out + (size_t)t * HIDDEN + n0 + (wn << 6) + ln;
        #pragma unroll
        for (int j = 0; j < 4; j++) orow[j << 4] = acc[i][j][r];
      }
    }
  }
}

extern "C" void kernel_launch(void* const* d_in, const int* in_sizes, int n_in,
                              void* d_out, int out_size, void* d_ws, size_t ws_size,
                              hipStream_t stream) {
  const float* x    = (const float*)d_in[0];
  const int*   ids  = (const int*)d_in[1];
  const float* gate = (const float*)d_in[2];
  const float* up   = (const float*)d_in[3];
  const float* down = (const float*)d_in[4];
  float* out = (float*)d_out;

  int T = in_sizes[0] / HIDDEN;              // 4096

  char* w = (char*)d_ws;
  int* hdr    = (int*)w;                                   // 1 KB
  int* src_of = (int*)(w + 1024);
  size_t off = 1024 + (size_t)T * 4;
  u16* Xg   = (u16*)(w + off);  off += (size_t)T * HIDDEN * 2;
  u16* Hb   = (u16*)(w + off);  off += (size_t)T * EINTER * 2;
  u16* gatet = (u16*)(w + off); off += (size_t)NEXP * HIDDEN * EINTER * 2;
  u16* upt   = (u16*)(w + off); off += (size_t)NEXP * HIDDEN * EINTER * 2;
  u16* downt = (u16*)(w + off); off += (size_t)NEXP * HIDDEN * EINTER * 2;

  int maxt = (T + 127) / 128 + (NEXP - 1) + 1;   // 40 worst-case tiles

  // z=0..2: weight transpose/convert (64 blocks x 4 tiles, 2-deep pipelined);
  // z=3: one block does token routing
  prep_kernel<<<dim3(64, NEXP, 4), 256, 0, stream>>>(gate, up, down, gatet, upt, downt,
                                                     ids, T, hdr, src_of);
  gather_kernel<<<T, 256, 0, stream>>>(x, src_of, Xg);
  gemm1_kernel<<<dim3(maxt, EINTER / 64), 256, 0, stream>>>(Xg, gatet, upt, Hb, hdr, T);
  gemm2_kernel<<<dim3(maxt, HIDDEN / 128), 256, 0, stream>>>(Hb, downt, out, src_of, hdr, T);
}

// Round 8
// 333.523 us; speedup vs baseline: 1.0001x; 1.0001x over previous
//
#include <hip/hip_runtime.h>
#include <hip/hip_bf16.h>
#include <math.h>

#define HIDDEN 2048
#define EINTER 1024
#define NEXP 8
#define VOCAB 100000
#define TPE (VOCAB / NEXP)   // 12500

typedef unsigned short u16;
typedef __attribute__((ext_vector_type(8))) short short8;   // 8 bf16 (4 VGPRs)
typedef __attribute__((ext_vector_type(4))) float f32x4;

__device__ __forceinline__ u16 f2bf(float f) {
  union { float f; unsigned u; } v; v.f = f;
  unsigned r = v.u + 0x7fffu + ((v.u >> 16) & 1u);   // RNE, finite inputs only
  return (u16)(r >> 16);
}

__device__ __forceinline__ float f4get(const float4& a, int i) {
  return i == 0 ? a.x : i == 1 ? a.y : i == 2 ? a.z : a.w;
}

__device__ __forceinline__ void gl2lds16(const u16* g, u16* l) {
  __builtin_amdgcn_global_load_lds(
      (const __attribute__((address_space(1))) unsigned int*)g,
      (__attribute__((address_space(3))) unsigned int*)l, 16, 0, 0);
}

// ---------------- routing (device body, fused into prep grid) ----------------
// hdr ints: [0..7]=cnt[e], [8..15]=off[e], [16]=n_tiles, [32..95]=worklist
__device__ void route_body(const int* __restrict__ ids, int T,
                           int* __restrict__ hdr, int* __restrict__ src_of) {
  __shared__ int cnt[NEXP], cur[NEXP];
  int tid = threadIdx.x;
  if (tid < NEXP) cnt[tid] = 0;
  __syncthreads();
  for (int t = tid; t < T; t += blockDim.x) {
    int id = ids[t]; id = min(max(id, 0), VOCAB - 1);
    int e = min(id / TPE, NEXP - 1);
    atomicAdd(&cnt[e], 1);
  }
  __syncthreads();
  if (tid == 0) {
    int acc = 0, nt = 0;
    for (int e = 0; e < NEXP; e++) {
      cur[e] = acc;
      hdr[e] = cnt[e];
      hdr[8 + e] = acc;
      int tiles = (cnt[e] + 127) >> 7;
      for (int m = 0; m < tiles; m++) hdr[32 + nt++] = (m << 3) | e;
      acc += cnt[e];
    }
    hdr[16] = nt;
  }
  __syncthreads();
  for (int t = tid; t < T; t += blockDim.x) {
    int id = ids[t]; id = min(max(id, 0), VOCAB - 1);
    int e = min(id / TPE, NEXP - 1);
    int pos = atomicAdd(&cur[e], 1);
    src_of[pos] = t;
  }
}

// ---------------- weight prep: fp32 [K][N] -> bf16 tiles [e][n_blk128][k_blk64] ----------------
// Latency model from R1/R6/R7: in-flight 16B loads/CU pinned at ~160-175 across all
// variants -> 2.2-2.3 TB/s. This version sustains 16-24 in flight per thread via a
// 3-set rotating register pipeline over 8 k-adjacent tiles per block; asm pins force
// the vmcnt wait AFTER all issues (sched_barrier alone failed 3x: VGPR 24-52).
__launch_bounds__(256, 4)
__global__ void prep_kernel(const float* __restrict__ gate, const float* __restrict__ up,
                            const float* __restrict__ down,
                            u16* __restrict__ gatet, u16* __restrict__ upt,
                            u16* __restrict__ downt,
                            const int* __restrict__ ids, int T,
                            int* __restrict__ hdr, int* __restrict__ src_of) {
  int z = blockIdx.z, e = blockIdx.y;
  if (z == 3) {
    if (blockIdx.x == 0 && blockIdx.y == 0) route_body(ids, T, hdr, src_of);
    return;
  }
  const float* W; u16* Wt; int K, N;
  if (z == 0)      { W = gate; Wt = gatet; K = 2048; N = 1024; }
  else if (z == 1) { W = up;   Wt = upt;   K = 2048; N = 1024; }
  else             { W = down; Wt = downt; K = 1024; N = 2048; }
  W += (size_t)e * K * N;
  int nkt = K >> 6, ntx = N >> 7;
  int bpc = nkt >> 3;                         // blocks per tn column (4 MLP, 2 down)
  int tn  = blockIdx.x / bpc;
  int tk0 = (blockIdx.x - tn * bpc) << 3;     // 8 consecutive k-tiles per block

  __shared__ u16 Ts[128 * 64];    // [n][k] swizzled, 16 KB
  int t = threadIdx.x;
  int kkb = (t >> 5) << 2;        // 0..28
  int cc  = (t & 31) << 2;        // n col 0..124

  const float* Wcol = W + (tn << 7) + cc;

  float4 sA[8], sB[8], sC[8];     // 3 rotating sets, 8 fp32x4 each

  // issue the 8 loads of k-tile (tk0+it_) into set S
  #define ISSUE(S, it_)                                                        \
    {                                                                          \
      const float* Wb_ = Wcol + (size_t)((tk0 + (it_)) << 6) * N;              \
      _Pragma("unroll")                                                        \
      for (int r = 0; r < 2; r++)                                              \
        _Pragma("unroll")                                                      \
        for (int i = 0; i < 4; i++)                                            \
          S[(r << 2) + i] =                                                    \
              *(const float4*)(Wb_ + (size_t)(kkb + (r << 5) + i) * N);        \
    }
  // liveness pin: forces all 8 loads of S complete HERE (issues cannot sink past)
  #define PIN(S)                                                               \
    {                                                                          \
      _Pragma("unroll")                                                        \
      for (int i = 0; i < 8; i++)                                              \
        asm volatile("" ::"v"(S[i].x), "v"(S[i].y), "v"(S[i].z), "v"(S[i].w)); \
    }
  #define CONVERT(S)                                                           \
    {                                                                          \
      _Pragma("unroll")                                                        \
      for (int r = 0; r < 2; r++) {                                            \
        int kk = kkb + (r << 5);                                               \
        int cbase = kk >> 3, klo = kk & 7;                                     \
        _Pragma("unroll")                                                      \
        for (int i2 = 0; i2 < 4; i2++) {                                       \
          int n_loc = cc + i2;                                                 \
          int cp = cbase ^ ((n_loc >> 2) & 7);                                 \
          unsigned lo = (unsigned)f2bf(f4get(S[(r << 2) + 0], i2)) |           \
                        ((unsigned)f2bf(f4get(S[(r << 2) + 1], i2)) << 16);    \
          unsigned hi = (unsigned)f2bf(f4get(S[(r << 2) + 2], i2)) |           \
                        ((unsigned)f2bf(f4get(S[(r << 2) + 3], i2)) << 16);    \
          uint2 pk; pk.x = lo; pk.y = hi;                                      \
          *(uint2*)&Ts[n_loc * 64 + (cp << 3) + klo] = pk;                     \
        }                                                                      \
      }                                                                        \
    }

  ISSUE(sA, 0);
  ISSUE(sB, 1);
  __builtin_amdgcn_sched_barrier(0);

  #pragma unroll
  for (int it = 0; it < 8; it++) {
    if (it + 2 < 8) {
      const int tgt = (it + 2) % 3;
      if (tgt == 2)      ISSUE(sC, it + 2)
      else if (tgt == 0) ISSUE(sA, it + 2)
      else               ISSUE(sB, it + 2)
      __builtin_amdgcn_sched_barrier(0);   // keep next-next issues ahead of waits
    }
    __syncthreads();                        // Ts free (phase2 of tile it-1 done)
    {
      const int cs = it % 3;
      if (cs == 0)      { PIN(sA) CONVERT(sA) }
      else if (cs == 1) { PIN(sB) CONVERT(sB) }
      else              { PIN(sC) CONVERT(sC) }
    }
    __syncthreads();
    // phase 2: b128 de-swizzle reads, contiguous 1KB/wave global writes (tile it)
    {
      size_t tile0 = ((size_t)e * ntx + tn) * (size_t)nkt + (tk0 + it);
      uint4* ob = (uint4*)Wt + tile0 * 1024;
      #pragma unroll
      for (int it2 = 0; it2 < 4; it2++) {
        int cid = (it2 << 8) + t;       // 0..1023
        int n_loc = cid >> 3, p = cid & 7;
        int cp = p ^ ((n_loc >> 2) & 7);
        uint4 val = *(const uint4*)&Ts[n_loc * 64 + (cp << 3)];
        ob[(n_loc << 3) + p] = val;
      }
    }
  }
  #undef ISSUE
  #undef PIN
  #undef CONVERT
}

// ---------------- gather tokens -> bf16 rows ----------------
__global__ void gather_kernel(const float* __restrict__ x,
                              const int* __restrict__ src_of,
                              u16* __restrict__ Xg) {
  int p = blockIdx.x;
  int t = src_of[p];
  int c = threadIdx.x;
  const float4* src = (const float4*)(x + (size_t)t * HIDDEN) + c * 2;
  float4 a = src[0], b = src[1];
  union { u16 s[8]; uint4 v; } o;
  o.s[0] = f2bf(a.x); o.s[1] = f2bf(a.y); o.s[2] = f2bf(a.z); o.s[3] = f2bf(a.w);
  o.s[4] = f2bf(b.x); o.s[5] = f2bf(b.y); o.s[6] = f2bf(b.z); o.s[7] = f2bf(b.w);
  *((uint4*)(Xg + (size_t)p * HIDDEN) + c) = o.v;
}

// ---------------- gemm1: H = silu(Xg@Wg) * (Xg@Wu), 128m x 64n tiles ----------------
// Single-buffer m97 structure. LDS tiles XOR-swizzled both sides (rule #21):
// linear gl2lds dest + pre-swizzled per-lane global source + XOR'd read column.
__launch_bounds__(256, 4)
__global__ void gemm1_kernel(const u16* __restrict__ Xg, const u16* __restrict__ gatet,
                             const u16* __restrict__ upt, u16* __restrict__ H,
                             const int* __restrict__ hdr, int T) {
  int ntile = hdr[16];
  if ((int)blockIdx.x >= ntile) return;
  int packed = hdr[32 + blockIdx.x];
  int e = packed & 7, mt = packed >> 3;
  int Me = hdr[e], base = hdr[8 + e];
  int row0 = base + (mt << 7);
  int valid = min(128, base + Me - row0);
  int n0 = blockIdx.y << 6;                          // 0..960
  size_t ebase = (size_t)e * (2048 * 1024);
  size_t tbase = ((size_t)(n0 >> 7) * 32) * 8192 + (size_t)((n0 >> 6) & 1) * 4096;
  const u16* gW = gatet + ebase + tbase;
  const u16* uW = upt   + ebase + tbase;

  __shared__ u16 As[128][64];   // 16 KB
  __shared__ u16 Bg[64][64];    // 8 KB
  __shared__ u16 Bu[64][64];    // 8 KB

  int tid = threadIdx.x, lane = tid & 63, wv = tid >> 6;
  int wm = wv >> 1, wn = wv & 1;
  int quad = lane >> 4, ln = lane & 15;
  // staging swizzle: LDS slot (row r = 8c+(lane>>3), chunk p = lane&7) receives
  // logical k-chunk p ^ (r&7); r&7 == lane>>3, so source chunk = (lane&7)^(lane>>3).
  int sw = (((lane & 7) ^ (lane >> 3)) << 3);        // u16 offset within 128B row

  f32x4 accG[4][2] = {};
  f32x4 accU[4][2] = {};

  for (int k0 = 0; k0 < 2048; k0 += 64) {
    size_t woff = (size_t)(k0 >> 6) * 8192 + ((size_t)(lane >> 3) << 6) + sw;
    __syncthreads();
    #pragma unroll
    for (int r = 0; r < 4; r++) {
      int c = (wv << 2) + r;                 // 16 chunks of 8 rows
      int arow = (c << 3) + (lane >> 3);
      int gr = min(row0 + arow, T - 1);      // clamped rows masked in epilogue
      gl2lds16(Xg + (size_t)gr * 2048 + k0 + sw, &As[0][0] + (c << 9));
    }
    #pragma unroll
    for (int r = 0; r < 2; r++) {
      int c = (wv << 1) + r;                 // 8 chunks, contiguous 128B segments
      gl2lds16(gW + woff + (c << 9), &Bg[0][0] + (c << 9));
      gl2lds16(uW + woff + (c << 9), &Bu[0][0] + (c << 9));
    }
    __syncthreads();
    #pragma unroll
    for (int s = 0; s < 2; s++) {
      // logical chunk (s<<2)|quad lives at physical chunk ^(row&7); row&7 == ln&7
      int col = ((((s << 2) | quad) ^ (ln & 7)) << 3);
      short8 a[4], bg[2], bu[2];
      #pragma unroll
      for (int i = 0; i < 4; i++) {
        int m = (wm << 6) + (i << 4) + ln;
        a[i] = *(const short8*)&As[m][col];
      }
      #pragma unroll
      for (int j = 0; j < 2; j++) {
        int n = (wn << 5) + (j << 4) + ln;
        bg[j] = *(const short8*)&Bg[n][col];
        bu[j] = *(const short8*)&Bu[n][col];
      }
      #pragma unroll
      for (int i = 0; i < 4; i++)
        #pragma unroll
        for (int j = 0; j < 2; j++) {
          accG[i][j] = __builtin_amdgcn_mfma_f32_16x16x32_bf16(a[i], bg[j], accG[i][j], 0, 0, 0);
          accU[i][j] = __builtin_amdgcn_mfma_f32_16x16x32_bf16(a[i], bu[j], accU[i][j], 0, 0, 0);
        }
    }
  }
  #pragma unroll
  for (int i = 0; i < 4; i++) {
    #pragma unroll
    for (int r = 0; r < 4; r++) {
      int rl = (wm << 6) + (i << 4) + (quad << 2) + r;
      if (rl < valid) {
        u16* orow = H + (size_t)(row0 + rl) * EINTER + n0 + (wn << 5) + ln;
        #pragma unroll
        for (int j = 0; j < 2; j++) {
          float g = accG[i][j][r], u = accU[i][j][r];
          orow[j << 4] = f2bf(g / (1.f + __expf(-g)) * u);
        }
      }
    }
  }
}

// ---------------- gemm2: out[src_of[p]] = H[p] @ down, 128x128, single-buffer + swizzle ----------------
__launch_bounds__(256, 4)
__global__ void gemm2_kernel(const u16* __restrict__ Hb, const u16* __restrict__ downt,
                             float* __restrict__ out, const int* __restrict__ src_of,
                             const int* __restrict__ hdr, int T) {
  int ntile = hdr[16];
  if ((int)blockIdx.x >= ntile) return;
  int packed = hdr[32 + blockIdx.x];
  int e = packed & 7, mt = packed >> 3;
  int Me = hdr[e], base = hdr[8 + e];
  int row0 = base + (mt << 7);
  int valid = min(128, base + Me - row0);
  int n0 = blockIdx.y << 7;
  const u16* wbase = downt + (size_t)e * (2048 * 1024)
                   + ((size_t)(n0 >> 7) * 16) * 8192;

  __shared__ u16 As[128][64];
  __shared__ u16 Bs[128][64];

  int tid = threadIdx.x, lane = tid & 63, wv = tid >> 6;
  int wm = wv >> 1, wn = wv & 1;
  int quad = lane >> 4, ln = lane & 15;
  int sw = (((lane & 7) ^ (lane >> 3)) << 3);

  f32x4 acc[4][4] = {};

  for (int k0 = 0; k0 < 1024; k0 += 64) {
    size_t woff = (size_t)(k0 >> 6) * 8192 + ((size_t)(lane >> 3) << 6) + sw;
    __syncthreads();
    #pragma unroll
    for (int r = 0; r < 4; r++) {
      int c = (wv << 2) + r;
      int arow = (c << 3) + (lane >> 3);
      int gr = min(row0 + arow, T - 1);
      gl2lds16(Hb + (size_t)gr * 1024 + k0 + sw, &As[0][0] + (c << 9));
      gl2lds16(wbase + woff + (c << 9), &Bs[0][0] + (c << 9));
    }
    __syncthreads();
    #pragma unroll
    for (int s = 0; s < 2; s++) {
      int col = ((((s << 2) | quad) ^ (ln & 7)) << 3);
      short8 a[4], b[4];
      #pragma unroll
      for (int i = 0; i < 4; i++) {
        int m = (wm << 6) + (i << 4) + ln;
        a[i] = *(const short8*)&As[m][col];
        int n = (wn << 6) + (i << 4) + ln;
        b[i] = *(const short8*)&Bs[n][col];
      }
      #pragma unroll
      for (int i = 0; i < 4; i++)
        #pragma unroll
        for (int j = 0; j < 4; j++)
          acc[i][j] = __builtin_amdgcn_mfma_f32_16x16x32_bf16(a[i], b[j], acc[i][j], 0, 0, 0);
    }
  }
  #pragma unroll
  for (int i = 0; i < 4; i++) {
    #pragma unroll
    for (int r = 0; r < 4; r++) {
      int rl = (wm << 6) + (i << 4) + (quad << 2) + r;
      if (rl < valid) {
        int t = src_of[row0 + rl];
        float* orow = out + (size_t)t * HIDDEN + n0 + (wn << 6) + ln;
        #pragma unroll
        for (int j = 0; j < 4; j++) orow[j << 4] = acc[i][j][r];
      }
    }
  }
}

extern "C" void kernel_launch(void* const* d_in, const int* in_sizes, int n_in,
                              void* d_out, int out_size, void* d_ws, size_t ws_size,
                              hipStream_t stream) {
  const float* x    = (const float*)d_in[0];
  const int*   ids  = (const int*)d_in[1];
  const float* gate = (const float*)d_in[2];
  const float* up   = (const float*)d_in[3];
  const float* down = (const float*)d_in[4];
  float* out = (float*)d_out;

  int T = in_sizes[0] / HIDDEN;              // 4096

  char* w = (char*)d_ws;
  int* hdr    = (int*)w;                                   // 1 KB
  int* src_of = (int*)(w + 1024);
  size_t off = 1024 + (size_t)T * 4;
  u16* Xg   = (u16*)(w + off);  off += (size_t)T * HIDDEN * 2;
  u16* Hb   = (u16*)(w + off);  off += (size_t)T * EINTER * 2;
  u16* gatet = (u16*)(w + off); off += (size_t)NEXP * HIDDEN * EINTER * 2;
  u16* upt   = (u16*)(w + off); off += (size_t)NEXP * HIDDEN * EINTER * 2;
  u16* downt = (u16*)(w + off); off += (size_t)NEXP * HIDDEN * EINTER * 2;

  int maxt = (T + 127) / 128 + (NEXP - 1) + 1;   // 40 worst-case tiles

  // z=0..2: weight transpose/convert (32 blocks x 8 tiles, 3-set reg pipeline);
  // z=3: one block does token routing
  prep_kernel<<<dim3(32, NEXP, 4), 256, 0, stream>>>(gate, up, down, gatet, upt, downt,
                                                     ids, T, hdr, src_of);
  gather_kernel<<<T, 256, 0, stream>>>(x, src_of, Xg);
  gemm1_kernel<<<dim3(maxt, EINTER / 64), 256, 0, stream>>>(Xg, gatet, upt, Hb, hdr, T);
  gemm2_kernel<<<dim3(maxt, HIDDEN / 128), 256, 0, stream>>>(Hb, downt, out, src_of, hdr, T);
}